// Round 16
// baseline (401.015 us; speedup 1.0000x reference)
//
#include <hip/hip_runtime.h>
#include <math.h>

#define EPSV 1e-5f

typedef __attribute__((ext_vector_type(8))) short short8;
typedef __attribute__((ext_vector_type(4))) float f32x4;

namespace {
constexpr int NB=8, C=512, NPIX=9216, K=32, NCLS=19;

// ws float offsets — bf16 regions sized in float-slots = elems/2. (r15 layout)
constexpr size_t o_WB    = 0;          // 131072 fl (512x512 bf16)
constexpr size_t o_CWB   = 131072;     // 8192 fl (32x512 bf16)
constexpr size_t o_A2    = 139264;     // 512
constexpr size_t o_B2    = 139776;     // 512
constexpr size_t o_C2    = 140288;     // 32
constexpr size_t o_X2    = 140320;     // 73728
constexpr size_t o_EW    = 214048;     // 131072 = NB*C*K (atomic fallback)
constexpr size_t o_ACNT  = 345120;     // 256 (contiguous after EW: one memset)
constexpr size_t o_EN    = 345376;     // 4096
constexpr size_t o_GAMMA = 349472;     // 4096
constexpr size_t o_XT    = 353568;     // 18874368 fl (73728x512 bf16), xT then hT in-place
constexpr size_t o_EPART = 19227936;   // 384*16384 float per-block E partials
constexpr size_t WS_NEED = (o_EPART + (size_t)384*16384) * 4;  // 102.1 MB — proven available

constexpr int NGRP   = 48;             // enc blocks per batch (384/8)
constexpr int NTILE  = 3;              // 64-px tiles per enc block
constexpr int CTILE  = 3;              // 64-px tiles per conv block (384*3 = 1152)
constexpr int CONV_LDS = (512*64 + 64*64)*2 + 64*4;       // 73984 B
constexpr int ENC_LDS  = 36864*2 + 2304*2 + 64*4;         // 78592 B
}

__device__ __forceinline__ ushort f2bf(float f){
  unsigned u = __float_as_uint(f);
  return (ushort)((u + 0x7FFFu + ((u>>16)&1u)) >> 16);
}
__device__ __forceinline__ float bf2f(ushort h){
  return __uint_as_float(((unsigned)h)<<16);
}

// ---------------- merged prep: Wb cvt | cwb cvt | bn2 affine + c2 (r6-verified) ----------------
__global__ __launch_bounds__(256) void k_prep(
    const float* __restrict__ convw, ushort* __restrict__ Wb,
    const float* __restrict__ cw,    ushort* __restrict__ cwb,
    const float* __restrict__ bn2w, const float* __restrict__ bn2b,
    const float* __restrict__ bn2m, const float* __restrict__ bn2v,
    float* __restrict__ pa, float* __restrict__ pb, float* __restrict__ c2g)
{
  const int bid = blockIdx.x, t = threadIdx.x;
  if (bid < 136){
    const float* src = (bid < 128) ? convw : cw;
    ushort* dst      = (bid < 128) ? Wb    : cwb;
    const int base   = (bid < 128) ? bid   : (bid - 128);
    int i = (base*256 + t)*8;
    float4 a = *(const float4*)(src+i), b = *(const float4*)(src+i+4);
    uint4 o;
    o.x = f2bf(a.x) | ((unsigned)f2bf(a.y)<<16);
    o.y = f2bf(a.z) | ((unsigned)f2bf(a.w)<<16);
    o.z = f2bf(b.x) | ((unsigned)f2bf(b.y)<<16);
    o.w = f2bf(b.z) | ((unsigned)f2bf(b.w)<<16);
    *(uint4*)(dst+i) = o;
  } else {
    for (int o = t; o < C; o += 256){
      float s = bn2w[o] * rsqrtf(bn2v[o] + EPSV);
      pa[o] = s;
      pb[o] = bn2b[o] - bn2m[o] * s;
    }
    int kk = t>>3, part = t&7;
    float s = 0.f;
    for (int c = part*64; c < part*64 + 64; c += 4){
      float4 w = *(const float4*)(cw + kk*512 + c);
      s += w.x*w.x + w.y*w.y + w.z*w.z + w.w*w.w;
    }
    s += __shfl_xor(s, 1);
    s += __shfl_xor(s, 2);
    s += __shfl_xor(s, 4);
    if (part == 0) c2g[kk] = s;
  }
}

// ---------------- transpose+cvt: x[b][c][n] -> xT[n][c] bf16 (r2-verified) ----------------
__global__ __launch_bounds__(256) void k_T(const float* __restrict__ x,
                                           ushort* __restrict__ xT){
  __shared__ float xs[64*68];
  const int bid = blockIdx.x;
  const int ct = bid & 7;
  const int nt = bid >> 3;
  const int b = nt / 144, ntl = nt % 144;
  const int c0 = ct*64, n0 = ntl*64;
  const int t = threadIdx.x;
  const float* src = x + ((size_t)b*C + c0)*NPIX + n0;
#pragma unroll
  for (int p = 0; p < 4; ++p){
    const int cr = p*16 + (t>>4);
    const int nc = (t&15)*4;
    *(float4*)(xs + cr*68 + nc) = *(const float4*)(src + (size_t)cr*NPIX + nc);
  }
  __syncthreads();
  const int nr = t>>2, ck = (t&3)*16;
  uint pk[8];
#pragma unroll
  for (int j = 0; j < 8; ++j){
    float f0 = xs[(ck + 2*j  )*68 + nr];
    float f1 = xs[(ck + 2*j+1)*68 + nr];
    pk[j] = (uint)f2bf(f0) | ((uint)f2bf(f1)<<16);
  }
  ushort* dst = xT + ((size_t)(b*NPIX + n0 + nr))*512 + c0 + ck;
  *(uint4*)(dst)   = make_uint4(pk[0],pk[1],pk[2],pk[3]);
  *(uint4*)(dst+8) = make_uint4(pk[4],pk[5],pk[6],pk[7]);
}

// ---------------- conv GEMM (bf16 MFMA) + BN + ReLU -> hT (in-place) + x2 ----------------
// r15 per-tile code verbatim; grid 384 blocks x 3 tiles (single residency wave)
__global__ __launch_bounds__(256,2) void k_conv(
  const ushort* __restrict__ Wb, ushort* __restrict__ xT,
  const float* __restrict__ pA2, const float* __restrict__ pB2,
  float* __restrict__ x2g)
{
  extern __shared__ char smem[];
  ushort* As  = (ushort*)smem;
  ushort* Bs  = As + 512*64;
  float*  x2s = (float*)(Bs + 64*64);
  const int t = threadIdx.x;
  const int wave = t>>6, lane = t&63;
  const int lg = lane>>4, l15 = lane&15;
  const int srow = t>>3, sq = t&7;

  for (int tt = 0; tt < CTILE; ++tt){
    const int n0 = blockIdx.x * (64*CTILE) + tt*64;
    // safe: only t<64 threads read x2s (x2g write below, same threads, program order)
    if (t < 64) x2s[t] = 0.f;

    f32x4 acc[8][4];
#pragma unroll
    for (int mi = 0; mi < 8; ++mi)
#pragma unroll
      for (int nj = 0; nj < 4; ++nj) acc[mi][nj] = (f32x4){0.f,0.f,0.f,0.f};

    for (int s = 0; s < 8; ++s) {
      const int c0 = s*64;
      __syncthreads();
#pragma unroll
      for (int p = 0; p < 16; ++p) {
        const int r = p*32 + srow;
        uint4 v = *(const uint4*)(Wb + r*512 + c0 + sq*8);
        *(uint4*)(As + r*64 + (((sq ^ (r&7))&7)<<3)) = v;
      }
#pragma unroll
      for (int p = 0; p < 2; ++p) {
        const int r = p*32 + srow;
        uint4 v = *(const uint4*)(xT + (size_t)(n0+r)*512 + c0 + sq*8);
        *(uint4*)(Bs + r*64 + (((sq ^ (r&7))&7)<<3)) = v;
      }
      __syncthreads();
#pragma unroll
      for (int kk = 0; kk < 2; ++kk) {
        short8 af[8], bfv[4];
#pragma unroll
        for (int mi = 0; mi < 8; ++mi) {
          const int r = wave*128 + mi*16 + l15;
          af[mi] = *(const short8*)(As + r*64 + ((((kk*4+lg) ^ (r&7))&7)<<3));
        }
#pragma unroll
        for (int nj = 0; nj < 4; ++nj) {
          const int r = nj*16 + l15;
          bfv[nj] = *(const short8*)(Bs + r*64 + ((((kk*4+lg) ^ (r&7))&7)<<3));
        }
#pragma unroll
        for (int mi = 0; mi < 8; ++mi)
#pragma unroll
          for (int nj = 0; nj < 4; ++nj)
            acc[mi][nj] = __builtin_amdgcn_mfma_f32_16x16x32_bf16(af[mi], bfv[nj], acc[mi][nj], 0,0,0);
      }
    }

    float x2p[4] = {0.f,0.f,0.f,0.f};
#pragma unroll
    for (int mi = 0; mi < 8; ++mi) {
      const int ob = wave*128 + mi*16 + lg*4;
      const float4 sa = *(const float4*)(pA2 + ob);
      const float4 sb = *(const float4*)(pB2 + ob);
#pragma unroll
      for (int nj = 0; nj < 4; ++nj) {
        const int n = n0 + nj*16 + l15;
        f32x4 a = acc[mi][nj];
        float h0 = fmaxf(fmaf(a[0], sa.x, sb.x), 0.f);
        float h1 = fmaxf(fmaf(a[1], sa.y, sb.y), 0.f);
        float h2 = fmaxf(fmaf(a[2], sa.z, sb.z), 0.f);
        float h3 = fmaxf(fmaf(a[3], sa.w, sb.w), 0.f);
        x2p[nj] += h0*h0 + h1*h1 + h2*h2 + h3*h3;
        uint2 pk;
        pk.x = f2bf(h0) | ((unsigned)f2bf(h1)<<16);
        pk.y = f2bf(h2) | ((unsigned)f2bf(h3)<<16);
        *(uint2*)(xT + (size_t)n*512 + ob) = pk;
      }
    }
#pragma unroll
    for (int nj = 0; nj < 4; ++nj) {
      float v = x2p[nj];
      v += __shfl_xor(v, 16);
      v += __shfl_xor(v, 32);
      if (lg == 0) atomicAdd(&x2s[nj*16 + l15], v);
    }
    __syncthreads();
    if (t < 64) x2g[n0 + t] = x2s[t];
  }
}

// ---------------- encoding: MFMA xc + softmax + MFMA E (r15-verified) ----------------
__global__ __launch_bounds__(256,2) void k_enc2(
  const ushort* __restrict__ hT, const float* __restrict__ x2g,
  const ushort* __restrict__ cwb, const float* __restrict__ scale,
  const float* __restrict__ c2g, float* __restrict__ Ebase,
  float* __restrict__ Acnt, int atomicE)
{
  extern __shared__ ushort sm16[];
  ushort* hbuf = sm16;               // hs[64][520] then hsT[512][72]
  ushort* Pl   = sm16 + 36864;       // [32][72]
  float*  x2s  = (float*)(sm16 + 36864 + 2304);  // [64]

  const int t = threadIdx.x, bid = blockIdx.x;
  const int wave = t>>6, lane = t&63, lg = lane>>4, l15 = lane&15;
  const int b = bid / NGRP;

  float sc[2][4], cv[2][4];
#pragma unroll
  for (int f=0; f<2; ++f)
#pragma unroll
    for (int i=0; i<4; ++i){
      int k = f*16 + lg*4 + i;
      sc[f][i] = scale[k];
      cv[f][i] = c2g[k];
    }

  f32x4 Eacc[2][8];
#pragma unroll
  for (int f=0; f<2; ++f)
#pragma unroll
    for (int nf=0; nf<8; ++nf) Eacc[f][nf] = (f32x4){0.f,0.f,0.f,0.f};
  float acs[2][4] = {{0.f,0.f,0.f,0.f},{0.f,0.f,0.f,0.f}};

  for (int tt = 0; tt < NTILE; ++tt){
    const int tile = bid*NTILE + tt;
    const size_t n0 = (size_t)tile*64;
    __syncthreads();
    {   // stage hT tile -> hs[px][520]
      const int px = t>>2, cq = t&3;
      const ushort* src = hT + (n0+px)*512 + cq*128;
      ushort* dst = hbuf + px*520 + cq*128;
#pragma unroll
      for (int i=0; i<16; ++i)
        *(uint4*)(dst + i*8) = *(const uint4*)(src + i*8);
    }
    if (t < 64) x2s[t] = x2g[n0 + t];
    __syncthreads();

    // ---- xc^T: D[m=k][n=px(wave's 16)], contraction c ----
    f32x4 xacc[2];
    xacc[0] = (f32x4){0.f,0.f,0.f,0.f};
    xacc[1] = (f32x4){0.f,0.f,0.f,0.f};
    {
      const ushort* hrow  = hbuf + (wave*16 + l15)*520 + lg*8;
      const ushort* arow0 = cwb + (l15)*512 + lg*8;
      const ushort* arow1 = cwb + (16 + l15)*512 + lg*8;
#pragma unroll
      for (int s = 0; s < 16; ++s){
        short8 bfr = *(const short8*)(hrow  + s*32);
        short8 a0  = *(const short8*)(arow0 + s*32);
        short8 a1  = *(const short8*)(arow1 + s*32);
        xacc[0] = __builtin_amdgcn_mfma_f32_16x16x32_bf16(a0, bfr, xacc[0], 0,0,0);
        xacc[1] = __builtin_amdgcn_mfma_f32_16x16x32_bf16(a1, bfr, xacc[1], 0,0,0);
      }
    }
    // ---- softmax over k (8 in-reg + shfl) ----
    const float x2v = x2s[wave*16 + l15];
    float sl[2][4];
    float mx = -1e30f;
#pragma unroll
    for (int f=0; f<2; ++f)
#pragma unroll
      for (int i=0; i<4; ++i){
        sl[f][i] = sc[f][i]*(x2v - 2.f*xacc[f][i] + cv[f][i]);
        mx = fmaxf(mx, sl[f][i]);
      }
    mx = fmaxf(mx, __shfl_xor(mx, 16));
    mx = fmaxf(mx, __shfl_xor(mx, 32));
    float pv[2][4];
    float ssum = 0.f;
#pragma unroll
    for (int f=0; f<2; ++f)
#pragma unroll
      for (int i=0; i<4; ++i){
        pv[f][i] = __expf(sl[f][i] - mx);
        ssum += pv[f][i];
      }
    ssum += __shfl_xor(ssum, 16);
    ssum += __shfl_xor(ssum, 32);
    const float inv = 1.f/ssum;
#pragma unroll
    for (int f=0; f<2; ++f)
#pragma unroll
      for (int i=0; i<4; ++i){
        float p = pv[f][i]*inv;
        ushort pb = f2bf(p);
        acs[f][i] += bf2f(pb);
        Pl[(f*16 + lg*4 + i)*72 + wave*16 + l15] = pb;
      }
    // ---- transpose read (hs -> regs) ----
    uint4 treg[16];
    {
      const ushort* src = hbuf + lane*520 + wave*128;
#pragma unroll
      for (int i=0; i<16; ++i) treg[i] = *(const uint4*)(src + i*8);
    }
    __syncthreads();
    {   // write hsT[c][72]
      ushort* dstT = hbuf + (size_t)(wave*128)*72 + lane;
#pragma unroll
      for (int i=0; i<16; ++i){
        uint4 v = treg[i];
#pragma unroll
        for (int w2=0; w2<4; ++w2){
          unsigned word = (&v.x)[w2];
          dstT[(i*8 + w2*2    )*72] = (ushort)(word & 0xFFFFu);
          dstT[(i*8 + w2*2 + 1)*72] = (ushort)(word >> 16);
        }
      }
    }
    __syncthreads();
    // ---- E: D[m=k][n=c(wave's 128)], contraction px ----
    short8 pa[2][2];
#pragma unroll
    for (int f=0; f<2; ++f)
#pragma unroll
      for (int ks=0; ks<2; ++ks)
        pa[f][ks] = *(const short8*)(Pl + (f*16 + l15)*72 + ks*32 + lg*8);
#pragma unroll
    for (int nf=0; nf<8; ++nf){
      const ushort* brow = hbuf + (size_t)(wave*128 + nf*16 + l15)*72 + lg*8;
      short8 b0 = *(const short8*)(brow);
      short8 b1 = *(const short8*)(brow + 32);
      Eacc[0][nf] = __builtin_amdgcn_mfma_f32_16x16x32_bf16(pa[0][0], b0, Eacc[0][nf], 0,0,0);
      Eacc[0][nf] = __builtin_amdgcn_mfma_f32_16x16x32_bf16(pa[0][1], b1, Eacc[0][nf], 0,0,0);
      Eacc[1][nf] = __builtin_amdgcn_mfma_f32_16x16x32_bf16(pa[1][0], b0, Eacc[1][nf], 0,0,0);
      Eacc[1][nf] = __builtin_amdgcn_mfma_f32_16x16x32_bf16(pa[1][1], b1, Eacc[1][nf], 0,0,0);
    }
  }

  // ---- flush E ----
  if (atomicE){
    float* pbase = Ebase + (size_t)b*16384;
#pragma unroll
    for (int f=0; f<2; ++f)
#pragma unroll
      for (int nf=0; nf<8; ++nf){
        const int c = wave*128 + nf*16 + l15;
        float* p = pbase + (size_t)c*32 + f*16 + lg*4;
        atomicAdd(p+0, Eacc[f][nf][0]);
        atomicAdd(p+1, Eacc[f][nf][1]);
        atomicAdd(p+2, Eacc[f][nf][2]);
        atomicAdd(p+3, Eacc[f][nf][3]);
      }
  } else {
    float* pbase = Ebase + (size_t)bid*16384;
#pragma unroll
    for (int f=0; f<2; ++f)
#pragma unroll
      for (int nf=0; nf<8; ++nf){
        const int c = wave*128 + nf*16 + l15;
        *(f32x4*)(pbase + (size_t)c*32 + f*16 + lg*4) = Eacc[f][nf];
      }
  }
  // ---- flush Acnt ----
#pragma unroll
  for (int f=0; f<2; ++f)
#pragma unroll
    for (int i=0; i<4; ++i){
      float v = acs[f][i];
      v += __shfl_xor(v, 1);
      v += __shfl_xor(v, 2);
      v += __shfl_xor(v, 4);
      v += __shfl_xor(v, 8);
      if (l15 == 0) atomicAdd(&Acnt[b*32 + f*16 + lg*4 + i], v);
    }
}

// ---------------- E reduce (float parts) -> bn1 -> relu -> mean_k -> en ----------------
__global__ __launch_bounds__(256) void k_en2(
    const float* __restrict__ Epart, const float* __restrict__ EwAtomic,
    const float* __restrict__ Acnt, const float* __restrict__ cw,
    const float* __restrict__ bn1w, const float* __restrict__ bn1b,
    const float* __restrict__ bn1m, const float* __restrict__ bn1v,
    float* __restrict__ en, int useAtomic)
{
  const int b = blockIdx.x >> 6;
  const int cchunk = blockIdx.x & 63;
  const int t = threadIdx.x;
  const int c_local = t >> 5, k = t & 31;
  const int c = cchunk*8 + c_local;

  float acc = 0.f;
  if (!useAtomic){
    const float* base = Epart + (size_t)b*NGRP*16384 + cchunk*256 + t;
    for (int g = 0; g < NGRP; ++g)
      acc += base[(size_t)g*16384];
  } else {
    acc = EwAtomic[(size_t)b*16384 + (size_t)c*32 + k];
  }
  float s1 = bn1w[k]*rsqrtf(bn1v[k]+EPSV);
  float t1 = bn1b[k] - bn1m[k]*s1;
  float e = acc - Acnt[b*32 + k]*cw[(size_t)k*512 + c];
  float v = fmaxf(fmaf(e, s1, t1), 0.f);
  v += __shfl_xor(v, 1);
  v += __shfl_xor(v, 2);
  v += __shfl_xor(v, 4);
  v += __shfl_xor(v, 8);
  v += __shfl_xor(v, 16);
  if (k == 0) en[(size_t)b*512 + c] = v*(1.f/32.f);
}

// ---------------- gamma / se ----------------
__global__ __launch_bounds__(512) void k_gate(
    const float* __restrict__ en, const float* __restrict__ fcw,
    const float* __restrict__ fcb, const float* __restrict__ sew,
    const float* __restrict__ seb, float* __restrict__ gamma,
    float* __restrict__ se_out)
{
    __shared__ float es[C];
    const int b = blockIdx.x;
    es[threadIdx.x] = en[(size_t)b * C + threadIdx.x];
    __syncthreads();
    {
        const int c = threadIdx.x;
        float z = fcb[c];
        const float* wr = fcw + (size_t)c * C;
        for (int i = 0; i < C; i += 4) {
            const float4 w = *(const float4*)(wr + i);
            z += w.x * es[i] + w.y * es[i + 1] + w.z * es[i + 2] + w.w * es[i + 3];
        }
        gamma[(size_t)b * C + c] = 1.f / (1.f + expf(-z));
    }
    if (threadIdx.x < NCLS * 8) {
        const int j = threadIdx.x >> 3, lane = threadIdx.x & 7;
        float p = 0.f;
        const float* swr = sew + (size_t)j * C;
        for (int i = lane * 64; i < lane * 64 + 64; i += 4) {
            const float4 w = *(const float4*)(swr + i);
            p += w.x * es[i] + w.y * es[i + 1] + w.z * es[i + 2] + w.w * es[i + 3];
        }
        p += __shfl_xor(p, 1);
        p += __shfl_xor(p, 2);
        p += __shfl_xor(p, 4);
        if (lane == 0) se_out[b * NCLS + j] = p + seb[j];
    }
}

// ---------------- out = relu(x * (1 + gamma)) ----------------
__global__ __launch_bounds__(256) void k_out(
    const float* __restrict__ x, const float* __restrict__ gamma,
    float* __restrict__ out)
{
    const int total4 = NB * C * NPIX / 4;
    for (int i = blockIdx.x * blockDim.x + threadIdx.x; i < total4;
         i += gridDim.x * blockDim.x) {
        const int flat = i * 4;
        const int bc = flat / NPIX;
        const float gsc = 1.f + gamma[bc];
        float4 v = *(const float4*)(x + flat);
        v.x = fmaxf(v.x * gsc, 0.f);
        v.y = fmaxf(v.y * gsc, 0.f);
        v.z = fmaxf(v.z * gsc, 0.f);
        v.w = fmaxf(v.w * gsc, 0.f);
        *(float4*)(out + flat) = v;
    }
}

extern "C" void kernel_launch(void* const* d_in, const int* in_sizes, int n_in,
                              void* d_out, int out_size, void* d_ws, size_t ws_size,
                              hipStream_t stream)
{
    const float* x     = (const float*)d_in[0];
    const float* convw = (const float*)d_in[1];
    const float* bn2w  = (const float*)d_in[2];
    const float* bn2b  = (const float*)d_in[3];
    const float* bn2m  = (const float*)d_in[4];
    const float* bn2v  = (const float*)d_in[5];
    const float* cw    = (const float*)d_in[6];
    const float* scale = (const float*)d_in[7];
    const float* bn1w  = (const float*)d_in[8];
    const float* bn1b  = (const float*)d_in[9];
    const float* bn1m  = (const float*)d_in[10];
    const float* bn1v  = (const float*)d_in[11];
    const float* fcw   = (const float*)d_in[12];
    const float* fcb   = (const float*)d_in[13];
    const float* sew   = (const float*)d_in[14];
    const float* seb   = (const float*)d_in[15];

    float* ws = (float*)d_ws;
    float* out = (float*)d_out;
    float* se_out = out + (size_t)NB * C * NPIX;

    ushort* Wb  = (ushort*)(ws + o_WB);
    ushort* cwb = (ushort*)(ws + o_CWB);
    ushort* xT  = (ushort*)(ws + o_XT);   // becomes hT after k_conv (in-place)

    const bool use_part = ws_size >= WS_NEED;
    float* Ebase = use_part ? (ws + o_EPART) : (ws + o_EW);
    const int useAtomic = use_part ? 0 : 1;

    (void)hipFuncSetAttribute((const void*)k_conv,
                              hipFuncAttributeMaxDynamicSharedMemorySize, CONV_LDS);
    (void)hipFuncSetAttribute((const void*)k_enc2,
                              hipFuncAttributeMaxDynamicSharedMemorySize, ENC_LDS);

    // zero EW + Acnt (contiguous; atomic targets — ws is poisoned once)
    hipMemsetAsync(ws + o_EW, 0, (size_t)(NB*C*K + 256) * sizeof(float), stream);

    k_prep<<<137, 256, 0, stream>>>(convw, Wb, cw, cwb,
                                    bn2w, bn2b, bn2m, bn2v,
                                    ws + o_A2, ws + o_B2, ws + o_C2);
    k_T<<<9216, 256, 0, stream>>>(x, xT);
    k_conv<<<384, 256, CONV_LDS, stream>>>(Wb, xT, ws + o_A2, ws + o_B2, ws + o_X2);
    k_enc2<<<384, 256, ENC_LDS, stream>>>(xT, ws + o_X2, cwb, scale, ws + o_C2,
                                          Ebase, ws + o_ACNT, useAtomic);
    k_en2<<<512, 256, 0, stream>>>(Ebase, ws + o_EW, ws + o_ACNT, cw,
                                   bn1w, bn1b, bn1m, bn1v, ws + o_EN, useAtomic);
    k_gate<<<8, 512, 0, stream>>>(ws + o_EN, fcw, fcb, sew, seb,
                                  ws + o_GAMMA, se_out);
    k_out<<<2048, 256, 0, stream>>>(x, ws + o_GAMMA, out);
}

// Round 17
// 293.405 us; speedup vs baseline: 1.3668x; 1.3668x over previous
//
#include <hip/hip_runtime.h>
#include <math.h>

#define EPSV 1e-5f

typedef __attribute__((ext_vector_type(8))) short short8;
typedef __attribute__((ext_vector_type(4))) float f32x4;

namespace {
constexpr int NB=8, C=512, NPIX=9216, K=32, NCLS=19;

// ws float offsets — bf16 regions sized in float-slots = elems/2. (r15 layout)
constexpr size_t o_WB    = 0;          // 131072 fl (512x512 bf16)
constexpr size_t o_CWB   = 131072;     // 8192 fl (32x512 bf16)
constexpr size_t o_A2    = 139264;     // 512
constexpr size_t o_B2    = 139776;     // 512
constexpr size_t o_C2    = 140288;     // 32
constexpr size_t o_X2    = 140320;     // 73728
constexpr size_t o_EW    = 214048;     // 131072 = NB*C*K (atomic fallback)
constexpr size_t o_ACNT  = 345120;     // 256 (contiguous after EW)
constexpr size_t o_EN    = 345376;     // 4096
constexpr size_t o_GAMMA = 349472;     // 4096
constexpr size_t o_XT    = 353568;     // 18874368 fl (73728x512 bf16), xT then hT in-place
constexpr size_t o_EPART = 19227936;   // 384*16384 float per-block E partials
constexpr size_t WS_NEED = (o_EPART + (size_t)384*16384) * 4;  // 102.1 MB — proven available

constexpr int NGRP   = 48;             // enc blocks per batch (384/8)
constexpr int NTILE  = 3;              // 64-px tiles per enc block
constexpr int ZERO_FL = NB*C*K + 256;  // 131328 floats to zero (EW + Acnt)
constexpr int CONV_LDS = (512*64 + 64*64)*2 + 64*4;       // 73984 B
constexpr int ENC_LDS  = 36864*2 + 2304*2 + 64*4;         // 78592 B
}

__device__ __forceinline__ ushort f2bf(float f){
  unsigned u = __float_as_uint(f);
  return (ushort)((u + 0x7FFFu + ((u>>16)&1u)) >> 16);
}
__device__ __forceinline__ float bf2f(ushort h){
  return __uint_as_float(((unsigned)h)<<16);
}

// ---------------- merged prep: Wb cvt | cwb cvt | bn2 affine + c2 | EW/Acnt zero ----------------
__global__ __launch_bounds__(256) void k_prep(
    const float* __restrict__ convw, ushort* __restrict__ Wb,
    const float* __restrict__ cw,    ushort* __restrict__ cwb,
    const float* __restrict__ bn2w, const float* __restrict__ bn2b,
    const float* __restrict__ bn2m, const float* __restrict__ bn2v,
    float* __restrict__ pa, float* __restrict__ pb, float* __restrict__ c2g,
    float* __restrict__ zero_dst)
{
  const int bid = blockIdx.x, t = threadIdx.x;
  if (bid < 136){
    const float* src = (bid < 128) ? convw : cw;
    ushort* dst      = (bid < 128) ? Wb    : cwb;
    const int base   = (bid < 128) ? bid   : (bid - 128);
    int i = (base*256 + t)*8;
    float4 a = *(const float4*)(src+i), b = *(const float4*)(src+i+4);
    uint4 o;
    o.x = f2bf(a.x) | ((unsigned)f2bf(a.y)<<16);
    o.y = f2bf(a.z) | ((unsigned)f2bf(a.w)<<16);
    o.z = f2bf(b.x) | ((unsigned)f2bf(b.y)<<16);
    o.w = f2bf(b.z) | ((unsigned)f2bf(b.w)<<16);
    *(uint4*)(dst+i) = o;
  } else if (bid == 136){
    for (int o = t; o < C; o += 256){
      float s = bn2w[o] * rsqrtf(bn2v[o] + EPSV);
      pa[o] = s;
      pb[o] = bn2b[o] - bn2m[o] * s;
    }
    int kk = t>>3, part = t&7;
    float s = 0.f;
    for (int c = part*64; c < part*64 + 64; c += 4){
      float4 w = *(const float4*)(cw + kk*512 + c);
      s += w.x*w.x + w.y*w.y + w.z*w.z + w.w*w.w;
    }
    s += __shfl_xor(s, 1);
    s += __shfl_xor(s, 2);
    s += __shfl_xor(s, 4);
    if (part == 0) c2g[kk] = s;
  } else {
    // blocks 137..265: zero EW + Acnt (replaces hipMemsetAsync dispatch)
    const int idx = ((bid - 137)*256 + t)*4;
    if (idx < ZERO_FL)
      *(float4*)(zero_dst + idx) = make_float4(0.f, 0.f, 0.f, 0.f);
  }
}

// ---------------- transpose+cvt: x[b][c][n] -> xT[n][c] bf16 (r2-verified) ----------------
__global__ __launch_bounds__(256) void k_T(const float* __restrict__ x,
                                           ushort* __restrict__ xT){
  __shared__ float xs[64*68];
  const int bid = blockIdx.x;
  const int ct = bid & 7;
  const int nt = bid >> 3;
  const int b = nt / 144, ntl = nt % 144;
  const int c0 = ct*64, n0 = ntl*64;
  const int t = threadIdx.x;
  const float* src = x + ((size_t)b*C + c0)*NPIX + n0;
#pragma unroll
  for (int p = 0; p < 4; ++p){
    const int cr = p*16 + (t>>4);
    const int nc = (t&15)*4;
    *(float4*)(xs + cr*68 + nc) = *(const float4*)(src + (size_t)cr*NPIX + nc);
  }
  __syncthreads();
  const int nr = t>>2, ck = (t&3)*16;
  uint pk[8];
#pragma unroll
  for (int j = 0; j < 8; ++j){
    float f0 = xs[(ck + 2*j  )*68 + nr];
    float f1 = xs[(ck + 2*j+1)*68 + nr];
    pk[j] = (uint)f2bf(f0) | ((uint)f2bf(f1)<<16);
  }
  ushort* dst = xT + ((size_t)(b*NPIX + n0 + nr))*512 + c0 + ck;
  *(uint4*)(dst)   = make_uint4(pk[0],pk[1],pk[2],pk[3]);
  *(uint4*)(dst+8) = make_uint4(pk[4],pk[5],pk[6],pk[7]);
}

// ---------------- conv GEMM (bf16 MFMA) + BN + ReLU -> hT (in-place) + x2 ----------------
// r15 config restored: 1152 blocks x 1 tile (r16's 384x3 regressed: 1.5 blocks/CU
// leaves half the CUs without a co-resident overlap partner -> latency exposed).
__global__ __launch_bounds__(256,2) void k_conv(
  const ushort* __restrict__ Wb, ushort* __restrict__ xT,
  const float* __restrict__ pA2, const float* __restrict__ pB2,
  float* __restrict__ x2g)
{
  extern __shared__ char smem[];
  ushort* As  = (ushort*)smem;
  ushort* Bs  = As + 512*64;
  float*  x2s = (float*)(Bs + 64*64);
  const int t = threadIdx.x;
  const int n0 = blockIdx.x * 64;
  const int wave = t>>6, lane = t&63;
  const int lg = lane>>4, l15 = lane&15;

  if (t < 64) x2s[t] = 0.f;

  f32x4 acc[8][4];
#pragma unroll
  for (int mi = 0; mi < 8; ++mi)
#pragma unroll
    for (int nj = 0; nj < 4; ++nj) acc[mi][nj] = (f32x4){0.f,0.f,0.f,0.f};

  const int srow = t>>3, sq = t&7;
  for (int s = 0; s < 8; ++s) {
    const int c0 = s*64;
    __syncthreads();
#pragma unroll
    for (int p = 0; p < 16; ++p) {
      const int r = p*32 + srow;
      uint4 v = *(const uint4*)(Wb + r*512 + c0 + sq*8);
      *(uint4*)(As + r*64 + (((sq ^ (r&7))&7)<<3)) = v;
    }
#pragma unroll
    for (int p = 0; p < 2; ++p) {
      const int r = p*32 + srow;
      uint4 v = *(const uint4*)(xT + (size_t)(n0+r)*512 + c0 + sq*8);
      *(uint4*)(Bs + r*64 + (((sq ^ (r&7))&7)<<3)) = v;
    }
    __syncthreads();
#pragma unroll
    for (int kk = 0; kk < 2; ++kk) {
      short8 af[8], bfv[4];
#pragma unroll
      for (int mi = 0; mi < 8; ++mi) {
        const int r = wave*128 + mi*16 + l15;
        af[mi] = *(const short8*)(As + r*64 + ((((kk*4+lg) ^ (r&7))&7)<<3));
      }
#pragma unroll
      for (int nj = 0; nj < 4; ++nj) {
        const int r = nj*16 + l15;
        bfv[nj] = *(const short8*)(Bs + r*64 + ((((kk*4+lg) ^ (r&7))&7)<<3));
      }
#pragma unroll
      for (int mi = 0; mi < 8; ++mi)
#pragma unroll
        for (int nj = 0; nj < 4; ++nj)
          acc[mi][nj] = __builtin_amdgcn_mfma_f32_16x16x32_bf16(af[mi], bfv[nj], acc[mi][nj], 0,0,0);
    }
  }

  float x2p[4] = {0.f,0.f,0.f,0.f};
#pragma unroll
  for (int mi = 0; mi < 8; ++mi) {
    const int ob = wave*128 + mi*16 + lg*4;
    const float4 sa = *(const float4*)(pA2 + ob);
    const float4 sb = *(const float4*)(pB2 + ob);
#pragma unroll
    for (int nj = 0; nj < 4; ++nj) {
      const int n = n0 + nj*16 + l15;
      f32x4 a = acc[mi][nj];
      float h0 = fmaxf(fmaf(a[0], sa.x, sb.x), 0.f);
      float h1 = fmaxf(fmaf(a[1], sa.y, sb.y), 0.f);
      float h2 = fmaxf(fmaf(a[2], sa.z, sb.z), 0.f);
      float h3 = fmaxf(fmaf(a[3], sa.w, sb.w), 0.f);
      x2p[nj] += h0*h0 + h1*h1 + h2*h2 + h3*h3;
      uint2 pk;
      pk.x = f2bf(h0) | ((unsigned)f2bf(h1)<<16);
      pk.y = f2bf(h2) | ((unsigned)f2bf(h3)<<16);
      *(uint2*)(xT + (size_t)n*512 + ob) = pk;
    }
  }
#pragma unroll
  for (int nj = 0; nj < 4; ++nj) {
    float v = x2p[nj];
    v += __shfl_xor(v, 16);
    v += __shfl_xor(v, 32);
    if (lg == 0) atomicAdd(&x2s[nj*16 + l15], v);
  }
  __syncthreads();
  if (t < 64) x2g[n0 + t] = x2s[t];
}

// ---------------- encoding: MFMA xc + softmax + MFMA E (r15-verified) ----------------
__global__ __launch_bounds__(256,2) void k_enc2(
  const ushort* __restrict__ hT, const float* __restrict__ x2g,
  const ushort* __restrict__ cwb, const float* __restrict__ scale,
  const float* __restrict__ c2g, float* __restrict__ Ebase,
  float* __restrict__ Acnt, int atomicE)
{
  extern __shared__ ushort sm16[];
  ushort* hbuf = sm16;               // hs[64][520] then hsT[512][72]
  ushort* Pl   = sm16 + 36864;       // [32][72]
  float*  x2s  = (float*)(sm16 + 36864 + 2304);  // [64]

  const int t = threadIdx.x, bid = blockIdx.x;
  const int wave = t>>6, lane = t&63, lg = lane>>4, l15 = lane&15;
  const int b = bid / NGRP;

  float sc[2][4], cv[2][4];
#pragma unroll
  for (int f=0; f<2; ++f)
#pragma unroll
    for (int i=0; i<4; ++i){
      int k = f*16 + lg*4 + i;
      sc[f][i] = scale[k];
      cv[f][i] = c2g[k];
    }

  f32x4 Eacc[2][8];
#pragma unroll
  for (int f=0; f<2; ++f)
#pragma unroll
    for (int nf=0; nf<8; ++nf) Eacc[f][nf] = (f32x4){0.f,0.f,0.f,0.f};
  float acs[2][4] = {{0.f,0.f,0.f,0.f},{0.f,0.f,0.f,0.f}};

  for (int tt = 0; tt < NTILE; ++tt){
    const int tile = bid*NTILE + tt;
    const size_t n0 = (size_t)tile*64;
    __syncthreads();
    {   // stage hT tile -> hs[px][520]
      const int px = t>>2, cq = t&3;
      const ushort* src = hT + (n0+px)*512 + cq*128;
      ushort* dst = hbuf + px*520 + cq*128;
#pragma unroll
      for (int i=0; i<16; ++i)
        *(uint4*)(dst + i*8) = *(const uint4*)(src + i*8);
    }
    if (t < 64) x2s[t] = x2g[n0 + t];
    __syncthreads();

    // ---- xc^T: D[m=k][n=px(wave's 16)], contraction c ----
    f32x4 xacc[2];
    xacc[0] = (f32x4){0.f,0.f,0.f,0.f};
    xacc[1] = (f32x4){0.f,0.f,0.f,0.f};
    {
      const ushort* hrow  = hbuf + (wave*16 + l15)*520 + lg*8;
      const ushort* arow0 = cwb + (l15)*512 + lg*8;
      const ushort* arow1 = cwb + (16 + l15)*512 + lg*8;
#pragma unroll
      for (int s = 0; s < 16; ++s){
        short8 bfr = *(const short8*)(hrow  + s*32);
        short8 a0  = *(const short8*)(arow0 + s*32);
        short8 a1  = *(const short8*)(arow1 + s*32);
        xacc[0] = __builtin_amdgcn_mfma_f32_16x16x32_bf16(a0, bfr, xacc[0], 0,0,0);
        xacc[1] = __builtin_amdgcn_mfma_f32_16x16x32_bf16(a1, bfr, xacc[1], 0,0,0);
      }
    }
    // ---- softmax over k (8 in-reg + shfl) ----
    const float x2v = x2s[wave*16 + l15];
    float sl[2][4];
    float mx = -1e30f;
#pragma unroll
    for (int f=0; f<2; ++f)
#pragma unroll
      for (int i=0; i<4; ++i){
        sl[f][i] = sc[f][i]*(x2v - 2.f*xacc[f][i] + cv[f][i]);
        mx = fmaxf(mx, sl[f][i]);
      }
    mx = fmaxf(mx, __shfl_xor(mx, 16));
    mx = fmaxf(mx, __shfl_xor(mx, 32));
    float pv[2][4];
    float ssum = 0.f;
#pragma unroll
    for (int f=0; f<2; ++f)
#pragma unroll
      for (int i=0; i<4; ++i){
        pv[f][i] = __expf(sl[f][i] - mx);
        ssum += pv[f][i];
      }
    ssum += __shfl_xor(ssum, 16);
    ssum += __shfl_xor(ssum, 32);
    const float inv = 1.f/ssum;
#pragma unroll
    for (int f=0; f<2; ++f)
#pragma unroll
      for (int i=0; i<4; ++i){
        float p = pv[f][i]*inv;
        ushort pb = f2bf(p);
        acs[f][i] += bf2f(pb);
        Pl[(f*16 + lg*4 + i)*72 + wave*16 + l15] = pb;
      }
    // ---- transpose read (hs -> regs) ----
    uint4 treg[16];
    {
      const ushort* src = hbuf + lane*520 + wave*128;
#pragma unroll
      for (int i=0; i<16; ++i) treg[i] = *(const uint4*)(src + i*8);
    }
    __syncthreads();
    {   // write hsT[c][72]
      ushort* dstT = hbuf + (size_t)(wave*128)*72 + lane;
#pragma unroll
      for (int i=0; i<16; ++i){
        uint4 v = treg[i];
#pragma unroll
        for (int w2=0; w2<4; ++w2){
          unsigned word = (&v.x)[w2];
          dstT[(i*8 + w2*2    )*72] = (ushort)(word & 0xFFFFu);
          dstT[(i*8 + w2*2 + 1)*72] = (ushort)(word >> 16);
        }
      }
    }
    __syncthreads();
    // ---- E: D[m=k][n=c(wave's 128)], contraction px ----
    short8 pa[2][2];
#pragma unroll
    for (int f=0; f<2; ++f)
#pragma unroll
      for (int ks=0; ks<2; ++ks)
        pa[f][ks] = *(const short8*)(Pl + (f*16 + l15)*72 + ks*32 + lg*8);
#pragma unroll
    for (int nf=0; nf<8; ++nf){
      const ushort* brow = hbuf + (size_t)(wave*128 + nf*16 + l15)*72 + lg*8;
      short8 b0 = *(const short8*)(brow);
      short8 b1 = *(const short8*)(brow + 32);
      Eacc[0][nf] = __builtin_amdgcn_mfma_f32_16x16x32_bf16(pa[0][0], b0, Eacc[0][nf], 0,0,0);
      Eacc[0][nf] = __builtin_amdgcn_mfma_f32_16x16x32_bf16(pa[0][1], b1, Eacc[0][nf], 0,0,0);
      Eacc[1][nf] = __builtin_amdgcn_mfma_f32_16x16x32_bf16(pa[1][0], b0, Eacc[1][nf], 0,0,0);
      Eacc[1][nf] = __builtin_amdgcn_mfma_f32_16x16x32_bf16(pa[1][1], b1, Eacc[1][nf], 0,0,0);
    }
  }

  // ---- flush E ----
  if (atomicE){
    float* pbase = Ebase + (size_t)b*16384;
#pragma unroll
    for (int f=0; f<2; ++f)
#pragma unroll
      for (int nf=0; nf<8; ++nf){
        const int c = wave*128 + nf*16 + l15;
        float* p = pbase + (size_t)c*32 + f*16 + lg*4;
        atomicAdd(p+0, Eacc[f][nf][0]);
        atomicAdd(p+1, Eacc[f][nf][1]);
        atomicAdd(p+2, Eacc[f][nf][2]);
        atomicAdd(p+3, Eacc[f][nf][3]);
      }
  } else {
    float* pbase = Ebase + (size_t)bid*16384;
#pragma unroll
    for (int f=0; f<2; ++f)
#pragma unroll
      for (int nf=0; nf<8; ++nf){
        const int c = wave*128 + nf*16 + l15;
        *(f32x4*)(pbase + (size_t)c*32 + f*16 + lg*4) = Eacc[f][nf];
      }
  }
  // ---- flush Acnt ----
#pragma unroll
  for (int f=0; f<2; ++f)
#pragma unroll
    for (int i=0; i<4; ++i){
      float v = acs[f][i];
      v += __shfl_xor(v, 1);
      v += __shfl_xor(v, 2);
      v += __shfl_xor(v, 4);
      v += __shfl_xor(v, 8);
      if (l15 == 0) atomicAdd(&Acnt[b*32 + f*16 + lg*4 + i], v);
    }
}

// ---------------- E reduce (float parts) -> bn1 -> relu -> mean_k -> en ----------------
__global__ __launch_bounds__(256) void k_en2(
    const float* __restrict__ Epart, const float* __restrict__ EwAtomic,
    const float* __restrict__ Acnt, const float* __restrict__ cw,
    const float* __restrict__ bn1w, const float* __restrict__ bn1b,
    const float* __restrict__ bn1m, const float* __restrict__ bn1v,
    float* __restrict__ en, int useAtomic)
{
  const int b = blockIdx.x >> 6;
  const int cchunk = blockIdx.x & 63;
  const int t = threadIdx.x;
  const int c_local = t >> 5, k = t & 31;
  const int c = cchunk*8 + c_local;

  float acc = 0.f;
  if (!useAtomic){
    const float* base = Epart + (size_t)b*NGRP*16384 + cchunk*256 + t;
    for (int g = 0; g < NGRP; ++g)
      acc += base[(size_t)g*16384];
  } else {
    acc = EwAtomic[(size_t)b*16384 + (size_t)c*32 + k];
  }
  float s1 = bn1w[k]*rsqrtf(bn1v[k]+EPSV);
  float t1 = bn1b[k] - bn1m[k]*s1;
  float e = acc - Acnt[b*32 + k]*cw[(size_t)k*512 + c];
  float v = fmaxf(fmaf(e, s1, t1), 0.f);
  v += __shfl_xor(v, 1);
  v += __shfl_xor(v, 2);
  v += __shfl_xor(v, 4);
  v += __shfl_xor(v, 8);
  v += __shfl_xor(v, 16);
  if (k == 0) en[(size_t)b*512 + c] = v*(1.f/32.f);
}

// ---------------- gamma / se ----------------
__global__ __launch_bounds__(512) void k_gate(
    const float* __restrict__ en, const float* __restrict__ fcw,
    const float* __restrict__ fcb, const float* __restrict__ sew,
    const float* __restrict__ seb, float* __restrict__ gamma,
    float* __restrict__ se_out)
{
    __shared__ float es[C];
    const int b = blockIdx.x;
    es[threadIdx.x] = en[(size_t)b * C + threadIdx.x];
    __syncthreads();
    {
        const int c = threadIdx.x;
        float z = fcb[c];
        const float* wr = fcw + (size_t)c * C;
        for (int i = 0; i < C; i += 4) {
            const float4 w = *(const float4*)(wr + i);
            z += w.x * es[i] + w.y * es[i + 1] + w.z * es[i + 2] + w.w * es[i + 3];
        }
        gamma[(size_t)b * C + c] = 1.f / (1.f + expf(-z));
    }
    if (threadIdx.x < NCLS * 8) {
        const int j = threadIdx.x >> 3, lane = threadIdx.x & 7;
        float p = 0.f;
        const float* swr = sew + (size_t)j * C;
        for (int i = lane * 64; i < lane * 64 + 64; i += 4) {
            const float4 w = *(const float4*)(swr + i);
            p += w.x * es[i] + w.y * es[i + 1] + w.z * es[i + 2] + w.w * es[i + 3];
        }
        p += __shfl_xor(p, 1);
        p += __shfl_xor(p, 2);
        p += __shfl_xor(p, 4);
        if (lane == 0) se_out[b * NCLS + j] = p + seb[j];
    }
}

// ---------------- out = relu(x * (1 + gamma)) ----------------
__global__ __launch_bounds__(256) void k_out(
    const float* __restrict__ x, const float* __restrict__ gamma,
    float* __restrict__ out)
{
    const int total4 = NB * C * NPIX / 4;
    for (int i = blockIdx.x * blockDim.x + threadIdx.x; i < total4;
         i += gridDim.x * blockDim.x) {
        const int flat = i * 4;
        const int bc = flat / NPIX;
        const float gsc = 1.f + gamma[bc];
        float4 v = *(const float4*)(x + flat);
        v.x = fmaxf(v.x * gsc, 0.f);
        v.y = fmaxf(v.y * gsc, 0.f);
        v.z = fmaxf(v.z * gsc, 0.f);
        v.w = fmaxf(v.w * gsc, 0.f);
        *(float4*)(out + flat) = v;
    }
}

extern "C" void kernel_launch(void* const* d_in, const int* in_sizes, int n_in,
                              void* d_out, int out_size, void* d_ws, size_t ws_size,
                              hipStream_t stream)
{
    const float* x     = (const float*)d_in[0];
    const float* convw = (const float*)d_in[1];
    const float* bn2w  = (const float*)d_in[2];
    const float* bn2b  = (const float*)d_in[3];
    const float* bn2m  = (const float*)d_in[4];
    const float* bn2v  = (const float*)d_in[5];
    const float* cw    = (const float*)d_in[6];
    const float* scale = (const float*)d_in[7];
    const float* bn1w  = (const float*)d_in[8];
    const float* bn1b  = (const float*)d_in[9];
    const float* bn1m  = (const float*)d_in[10];
    const float* bn1v  = (const float*)d_in[11];
    const float* fcw   = (const float*)d_in[12];
    const float* fcb   = (const float*)d_in[13];
    const float* sew   = (const float*)d_in[14];
    const float* seb   = (const float*)d_in[15];

    float* ws = (float*)d_ws;
    float* out = (float*)d_out;
    float* se_out = out + (size_t)NB * C * NPIX;

    ushort* Wb  = (ushort*)(ws + o_WB);
    ushort* cwb = (ushort*)(ws + o_CWB);
    ushort* xT  = (ushort*)(ws + o_XT);   // becomes hT after k_conv (in-place)

    const bool use_part = ws_size >= WS_NEED;
    float* Ebase = use_part ? (ws + o_EPART) : (ws + o_EW);
    const int useAtomic = use_part ? 0 : 1;

    (void)hipFuncSetAttribute((const void*)k_conv,
                              hipFuncAttributeMaxDynamicSharedMemorySize, CONV_LDS);
    (void)hipFuncSetAttribute((const void*)k_enc2,
                              hipFuncAttributeMaxDynamicSharedMemorySize, ENC_LDS);

    k_prep<<<266, 256, 0, stream>>>(convw, Wb, cw, cwb,
                                    bn2w, bn2b, bn2m, bn2v,
                                    ws + o_A2, ws + o_B2, ws + o_C2, ws + o_EW);
    k_T<<<9216, 256, 0, stream>>>(x, xT);
    k_conv<<<1152, 256, CONV_LDS, stream>>>(Wb, xT, ws + o_A2, ws + o_B2, ws + o_X2);
    k_enc2<<<384, 256, ENC_LDS, stream>>>(xT, ws + o_X2, cwb, scale, ws + o_C2,
                                          Ebase, ws + o_ACNT, useAtomic);
    k_en2<<<512, 256, 0, stream>>>(Ebase, ws + o_EW, ws + o_ACNT, cw,
                                   bn1w, bn1b, bn1m, bn1v, ws + o_EN, useAtomic);
    k_gate<<<8, 512, 0, stream>>>(ws + o_EN, fcw, fcb, sew, seb,
                                  ws + o_GAMMA, se_out);
    k_out<<<2048, 256, 0, stream>>>(x, ws + o_GAMMA, out);
}